// Round 14
// baseline (10912.569 us; speedup 1.0000x reference)
//
#include <hip/hip_runtime.h>

typedef __attribute__((ext_vector_type(4))) float f32x4;
typedef __attribute__((ext_vector_type(8))) short short8;
typedef __attribute__((ext_vector_type(4))) unsigned short ushort4v;

__device__ __forceinline__ unsigned short rne_bf16(float f) {
  unsigned int u = __builtin_bit_cast(unsigned int, f);
  u += 0x7FFFu + ((u >> 16) & 1u);
  return (unsigned short)(u >> 16);
}

__device__ __forceinline__ void async16(void* lds, const void* g) {
  __builtin_amdgcn_global_load_lds(
      (const __attribute__((address_space(1))) void*)g,
      (__attribute__((address_space(3))) void*)lds, 16, 0, 0);
}

__device__ __forceinline__ f32x4 mfma16(short8 a, short8 b, f32x4 c) {
  return __builtin_amdgcn_mfma_f32_16x16x32_bf16(a, b, c, 0, 0, 0);
}

// ---------------- f32 -> bf16 cast (vectorized, grid-stride) ----------------
__global__ __launch_bounds__(256) void cast_k(const float* __restrict__ in,
                                              unsigned short* __restrict__ out,
                                              int n4) {
  int stride = gridDim.x * 256;
  for (int i = blockIdx.x * 256 + threadIdx.x; i < n4; i += stride) {
    float4 v = ((const float4*)in)[i];
    ushort4v o = {rne_bf16(v.x), rne_bf16(v.y), rne_bf16(v.z), rne_bf16(v.w)};
    ((ushort4v*)out)[i] = o;
  }
}

// ---------------- all-inputs cast in ONE dispatch (big-ws path) --------------
__global__ __launch_bounds__(256) void cast_all(const float* __restrict__ x1,
                                                const float* __restrict__ x2,
                                                const float* __restrict__ Wq,
                                                const float* __restrict__ Wk,
                                                const float* __restrict__ Wv,
                                                const float* __restrict__ Wp,
                                                unsigned short* __restrict__ x1b,
                                                unsigned short* __restrict__ x2b,
                                                unsigned short* __restrict__ Wb4) {
  const int stride = gridDim.x * 256;
  for (int i = blockIdx.x * 256 + threadIdx.x; i < 33554432; i += stride) {
    const float* src;
    unsigned short* dst;
    int off;
    if (i < 8388608) {
      src = x1; dst = x1b; off = i;
    } else if (i < 16777216) {
      src = x2; dst = x2b; off = i - 8388608;
    } else {
      const int w = (i - 16777216) >> 22;
      off = (i - 16777216) & 4194303;
      src = (w == 0) ? Wq : (w == 1) ? Wk : (w == 2) ? Wv : Wp;
      dst = Wb4 + (size_t)w * 16777216;
    }
    float4 v = ((const float4*)src)[off];
    ushort4v o = {rne_bf16(v.x), rne_bf16(v.y), rne_bf16(v.z), rne_bf16(v.w)};
    ((ushort4v*)dst)[off] = o;
  }
}

// ============ 256x256-tile GEMM: C = A @ B^T (bf16 in, K%32==0, K>=64) =======
// NEW (R14): BK=32, 64 KiB LDS (A: 2 bufs of 256x32 shorts at d*8192; B: same
// at 16384 + d*8192) -> 2 BLOCKS/CU. Rationale: all prior schedules (43-52%
// MfmaUtil) ran 1 block/CU in barrier-lockstep; per-CU pipes are balanced
// (MFMA 2483 cyc vs LDS 2304 cyc per BK=64 tile) but serialize without a
// co-resident block. 2 blocks/CU -> block-level MFMA/LDS overlap (m114
// mechanism), time -> max(pipes) not sum.
// Loop per K-tile t: READ12(buf t&1) | MFMA32 | barrier (reads done) |
// STG(t+2 -> buf t&1) | vmcnt(4) (retires t+1's stage; publish at barrier) |
// barrier. Tail: vmcnt(0) when no stage. Prologue: STG(0),STG(1),vmcnt(4).
// Same proven swizzle (32-short rows, chunk-XOR), same epilogues.
// blockIdx.z selects (A, W, dst, scale) for the merged-QKV launch.
// MODE 0: QKV proj -> bf16 head-transposed dst[(b*16+h)][i][tok], *scale
// MODE 3: out proj -> f32 outF[m*4096+n] + bias[n]
template <int MODE>
__global__ __launch_bounds__(512, 4) void gemm256(const unsigned short* __restrict__ A1,
                                                  const unsigned short* __restrict__ A2,
                                                  const unsigned short* __restrict__ Bb,
                                                  size_t wstride,
                                                  float* __restrict__ outF,
                                                  unsigned short* __restrict__ outB0,
                                                  const float* __restrict__ bias,
                                                  int K, int lda, int ldb,
                                                  float scale0, float scale1, int gx) {
  __shared__ unsigned short lds[32768];  // 64 KiB -> 2 blocks/CU
  const int tid = threadIdx.x;
  const int lane = tid & 63;
  const int wid = tid >> 6;
  const int wm = wid >> 2;  // 0..1 -> 128 rows each
  const int wn = wid & 3;   // 0..3 -> 64 cols each
  const int z = blockIdx.z;
  const unsigned short* A = z ? A2 : A1;
  const unsigned short* B = Bb + (size_t)z * wstride;
  unsigned short* outB = (MODE == 0) ? outB0 + (size_t)z * 33554432 : outB0;
  const float scale = z ? scale1 : scale0;
  int lin = blockIdx.x;
  lin = (lin & 7) * (gridDim.x >> 3) + (lin >> 3);  // XCD swizzle (grid%8==0)
  const int bx = lin % gx;
  const int by = lin / gx;
  const int m0 = by * 256, n0 = bx * 256;
  const int NT = K >> 5;  // BK = 32

  // staging: thread t covers LDS slot p = tid (+512): row=p>>2, chunk=p&3
  const int gsw8 = (((tid & 3) ^ ((tid >> 3) & 3))) * 8;  // pre-swizzled col
  const unsigned short* gA = A + (size_t)(m0 + (tid >> 2)) * lda + gsw8;
  const unsigned short* gB = B + (size_t)(n0 + (tid >> 2)) * ldb + gsw8;
  const size_t astep = (size_t)128 * lda;
  const size_t bstep = (size_t)128 * ldb;
  unsigned short* ld0 = &lds[tid * 8];

// stage K-tile T (cols T*32..T*32+31) into buffer D: 4 gloads (A 2, B 2)
#define STG(T, D) do { \
    const unsigned short* sA_ = gA + (size_t)(T) * 32; \
    unsigned short* dA_ = ld0 + (D) * 8192; \
    async16(dA_, sA_); async16(dA_ + 4096, sA_ + astep); \
    const unsigned short* sB_ = gB + (size_t)(T) * 32; \
    unsigned short* dB_ = ld0 + 16384 + (D) * 8192; \
    async16(dB_, sB_); async16(dB_ + 4096, sB_ + bstep); } while (0)

  // ds_read addresses (swizzled chunk; conflict-free, proven pattern)
  const int rl = lane & 15;
  const int ch = (lane >> 4) ^ ((rl >> 1) & 3);
  const int aidx = wm * 4096 + rl * 32 + ch * 8;   // + d*8192 + f*512
  const int bidx = wn * 2048 + rl * 32 + ch * 8;   // + 16384 + d*8192 + s*512

  short8 af[8], bf[4];
#define READ12(D) do { \
    _Pragma("unroll") \
    for (int r_ = 0; r_ < 8; ++r_) \
      af[r_] = *(const short8*)&lds[(D) * 8192 + aidx + r_ * 512]; \
    _Pragma("unroll") \
    for (int s_ = 0; s_ < 4; ++s_) \
      bf[s_] = *(const short8*)&lds[16384 + (D) * 8192 + bidx + s_ * 512]; \
  } while (0)

  f32x4 acc[8][4];
#pragma unroll
  for (int r = 0; r < 8; ++r)
#pragma unroll
    for (int s = 0; s < 4; ++s) acc[r][s] = (f32x4){0.f, 0.f, 0.f, 0.f};

#define MFMA32() do { \
    __builtin_amdgcn_s_setprio(1); \
    _Pragma("unroll") \
    for (int r_ = 0; r_ < 8; ++r_) \
      _Pragma("unroll") \
      for (int s_ = 0; s_ < 4; ++s_) acc[r_][s_] = mfma16(af[r_], bf[s_], acc[r_][s_]); \
    __builtin_amdgcn_s_setprio(0); \
  } while (0)

  // ---- prologue: stage tiles 0,1; retire tile 0; publish
  STG(0, 0); STG(1, 1);
  asm volatile("s_waitcnt vmcnt(4)" ::: "memory");
  __builtin_amdgcn_s_barrier();

  for (int t = 0; t < NT; ++t) {
    const int d = t & 1;
    READ12(d);
    __builtin_amdgcn_sched_barrier(0);
    MFMA32();
    __builtin_amdgcn_s_barrier();      // all waves done reading buf d
    if (t + 2 < NT) {
      STG(t + 2, d);                   // overwrite buf d for tile t+2
      asm volatile("s_waitcnt vmcnt(4)" ::: "memory");  // retire t+1's stage
    } else if (t + 1 < NT) {
      asm volatile("s_waitcnt vmcnt(0)" ::: "memory");  // retire t+1's stage
    }
    __builtin_amdgcn_s_barrier();      // publish buf d^1 for iter t+1
  }
#undef STG
#undef READ12
#undef MFMA32

  // ---- epilogue: C frag col = lane&15, row = (lane>>4)*4 + j
  const int fcol = lane & 15;
  const int frow = (lane >> 4) * 4;
#pragma unroll
  for (int r = 0; r < 8; ++r) {
#pragma unroll
    for (int s = 0; s < 4; ++s) {
      f32x4 v = acc[r][s];
      const int m = m0 + wm * 128 + r * 16 + frow;
      const int n = n0 + wn * 64 + s * 16 + fcol;
      if (MODE == 0) {
        ushort4v p;
#pragma unroll
        for (int j = 0; j < 4; ++j) p[j] = rne_bf16(v[j] * scale);
        size_t d2 = ((size_t)((m >> 8) * 16 + (n >> 8))) * 65536 +
                    (size_t)(n & 255) * 256 + (m & 255);
        *(ushort4v*)&outB[d2] = p;
      } else {
        float bv = bias[n];
#pragma unroll
        for (int j = 0; j < 4; ++j) outF[(size_t)(m + j) * 4096 + n] = v[j] + bv;
      }
    }
  }
}

// ============ fused per-head attention: S = Qt@Kt^T, softmax, out = P@Vt^T ===
// (unchanged — near HBM floor)
__global__ __launch_bounds__(256) void attn_fused(const unsigned short* __restrict__ Qt,
                                                  const unsigned short* __restrict__ Kt,
                                                  const unsigned short* __restrict__ Vt,
                                                  float* __restrict__ outA,
                                                  unsigned short* __restrict__ outXb) {
  __shared__ unsigned short sh[34560];
  const int tid = threadIdx.x;
  const int lane = tid & 63;
  const int wid = tid >> 6;
  const int z = blockIdx.y;
  const int m0 = blockIdx.x * 64;
  const int wm = wid >> 1;
  const int wn = wid & 1;
  const int fcol = lane & 15;
  const int kslot = (lane >> 4) * 8;
  const int frow = (lane >> 4) * 4;

  const unsigned short* Qh = Qt + (size_t)z * 65536;
  const unsigned short* Kh = Kt + (size_t)z * 65536;
  const unsigned short* Vh = Vt + (size_t)z * 65536;
  float* redM = (float*)&sh[33536];
  float* redS = redM + 128;

  f32x4 acc[2][8];
#pragma unroll
  for (int r = 0; r < 2; ++r)
#pragma unroll
    for (int s = 0; s < 8; ++s) acc[r][s] = (f32x4){0.f, 0.f, 0.f, 0.f};

  {
    const int arow = tid >> 2;
    const int acol = (tid & 3) * 8;
    const unsigned short* gQ = Qh + (size_t)(m0 + arow) * 256 + acol;
    const unsigned short* gK = Kh + (size_t)arow * 256 + acol;
    unsigned short* lA = &sh[tid * 8];
    unsigned short* lB = &sh[2048 + tid * 8];

    for (int kt = 0; kt < 256; kt += 32) {
      __syncthreads();
      async16(lA, gQ + kt);
      async16(lB, gK + kt);
      async16(lB + 2048, gK + (size_t)64 * 256 + kt);
      async16(lB + 4096, gK + (size_t)128 * 256 + kt);
      async16(lB + 6144, gK + (size_t)192 * 256 + kt);
      __syncthreads();

      short8 a[2], b[8];
#pragma unroll
      for (int r = 0; r < 2; ++r)
        a[r] = *(const short8*)&sh[(wm * 32 + r * 16 + fcol) * 32 + kslot];
#pragma unroll
      for (int s = 0; s < 8; ++s)
        b[s] = *(const short8*)&sh[2048 + (wn * 128 + s * 16 + fcol) * 32 + kslot];
#pragma unroll
      for (int r = 0; r < 2; ++r)
#pragma unroll
        for (int s = 0; s < 8; ++s)
          acc[r][s] = mfma16(a[r], b[s], acc[r][s]);
    }
  }
  __syncthreads();

#pragma unroll
  for (int r = 0; r < 2; ++r) {
#pragma unroll
    for (int j = 0; j < 4; ++j) {
      float m = acc[r][0][j];
#pragma unroll
      for (int s = 1; s < 8; ++s) m = fmaxf(m, acc[r][s][j]);
#pragma unroll
      for (int off = 1; off < 16; off <<= 1) m = fmaxf(m, __shfl_xor(m, off, 64));
      if (fcol == 0) redM[(wm * 32 + r * 16 + frow + j) * 2 + wn] = m;
    }
  }
  __syncthreads();
#pragma unroll
  for (int r = 0; r < 2; ++r) {
#pragma unroll
    for (int j = 0; j < 4; ++j) {
      const int rl = wm * 32 + r * 16 + frow + j;
      const float m = fmaxf(redM[rl * 2 + 0], redM[rl * 2 + 1]);
      float sum = 0.f;
#pragma unroll
      for (int s = 0; s < 8; ++s) {
        float e = __expf(acc[r][s][j] - m);
        acc[r][s][j] = e;
        sum += e;
      }
#pragma unroll
      for (int off = 1; off < 16; off <<= 1) sum += __shfl_xor(sum, off, 64);
      if (fcol == 0) redS[rl * 2 + wn] = sum;
    }
  }
  __syncthreads();
#pragma unroll
  for (int r = 0; r < 2; ++r) {
#pragma unroll
    for (int j = 0; j < 4; ++j) {
      const int rl = wm * 32 + r * 16 + frow + j;
      const float inv = 1.0f / (redS[rl * 2 + 0] + redS[rl * 2 + 1]);
      const size_t rowo = (size_t)z * 65536 + (size_t)(m0 + rl) * 256;
#pragma unroll
      for (int s = 0; s < 8; ++s) {
        const int col = wn * 128 + s * 16 + fcol;
        const float p = acc[r][s][j] * inv;
        outA[rowo + col] = p;
        sh[16384 + rl * 268 + col] = rne_bf16(p);
      }
    }
  }
  __syncthreads();

  const unsigned short* gV = Vh + (size_t)(tid >> 2) * 256 + (tid & 3) * 8;
#define STGV(kt, vb) do { \
    _Pragma("unroll") \
    for (int k_ = 0; k_ < 4; ++k_) \
      async16(&sh[(vb) + tid * 8 + k_ * 2048], \
              gV + (size_t)k_ * 64 * 256 + (kt) * 32); } while (0)

  STGV(0, 0); STGV(1, 8192);
  asm volatile("s_waitcnt vmcnt(4)" ::: "memory");
  __builtin_amdgcn_s_barrier();

  f32x4 acc2[2][8];
#pragma unroll
  for (int r = 0; r < 2; ++r)
#pragma unroll
    for (int s = 0; s < 8; ++s) acc2[r][s] = (f32x4){0.f, 0.f, 0.f, 0.f};

  for (int kt = 0; kt < 8; ++kt) {
    const int vb = (kt & 1) * 8192;
    short8 a2[2], b2[8];
#pragma unroll
    for (int r = 0; r < 2; ++r)
      a2[r] = *(const short8*)&sh[16384 + (wm * 32 + r * 16 + fcol) * 268 + kt * 32 + kslot];
#pragma unroll
    for (int s = 0; s < 8; ++s)
      b2[s] = *(const short8*)&sh[vb + (wn * 128 + s * 16 + fcol) * 32 + kslot];
#pragma unroll
    for (int r = 0; r < 2; ++r)
#pragma unroll
      for (int s = 0; s < 8; ++s)
        acc2[r][s] = mfma16(a2[r], b2[s], acc2[r][s]);
    __builtin_amdgcn_s_barrier();
    if (kt + 2 < 8) {
      STGV(kt + 2, vb);
      asm volatile("s_waitcnt vmcnt(4)" ::: "memory");
    } else {
      asm volatile("s_waitcnt vmcnt(0)" ::: "memory");
    }
    __builtin_amdgcn_s_barrier();
  }
#undef STGV

#pragma unroll
  for (int r = 0; r < 2; ++r) {
#pragma unroll
    for (int s = 0; s < 8; ++s) {
      f32x4 v = acc2[r][s];
      const int i0 = m0 + wm * 32 + r * 16 + frow;
      const int c = wn * 128 + s * 16 + fcol;
#pragma unroll
      for (int j = 0; j < 4; ++j) {
        size_t d = ((size_t)((z >> 4) * 256 + i0 + j)) * 4096 + (z & 15) * 256 + c;
        outXb[d] = rne_bf16(v[j]);
      }
    }
  }
}

// -----------------------------------------------------------------------------
extern "C" void kernel_launch(void* const* d_in, const int* in_sizes, int n_in,
                              void* d_out, int out_size, void* d_ws, size_t ws_size,
                              hipStream_t stream) {
  const float* x1 = (const float*)d_in[0];
  const float* x2 = (const float*)d_in[1];
  const float* Wq = (const float*)d_in[2];
  const float* Wk = (const float*)d_in[3];
  const float* Wv = (const float*)d_in[4];
  const float* Wp = (const float*)d_in[5];
  const float* bp = (const float*)d_in[6];

  float* outX = (float*)d_out;                   // x: [8192,4096] f32
  float* outA = outX + (size_t)33554432;         // attn: [512,256,256] f32

  unsigned short* Qt  = (unsigned short*)d_ws;   // [512][256][256] head-transposed
  unsigned short* Kt  = Qt + 33554432;
  unsigned short* Vt  = Kt + 33554432;
  unsigned short* x1b = Vt + 33554432;           // x1 bf16
  unsigned short* x2b = x1b + 33554432;          // x2 bf16; later out_x bf16

  const float SCALE = 0.0625f;  // 256^-0.5
  const bool big = ws_size >= 469762048ULL;

  if (big) {
    unsigned short* Wb4 = x2b + 33554432;        // [4][4096][4096] bf16
    cast_all<<<2048, 256, 0, stream>>>(x1, x2, Wq, Wk, Wv, Wp, x1b, x2b, Wb4);
    // merged QKV: z=0: Q=(x1b@Wq^T)*SCALE->Qt; z=1: K->Kt; z=2: V->Vt
    gemm256<0><<<dim3(512, 1, 3), 512, 0, stream>>>(
        x1b, x2b, Wb4, (size_t)16777216, nullptr, Qt, nullptr,
        4096, 4096, 4096, SCALE, 1.0f, 16);
    attn_fused<<<dim3(4, 512), 256, 0, stream>>>(Qt, Kt, Vt, outA, x2b);
    // x = out @ Wp^T + bp -> d_out
    gemm256<3><<<dim3(512, 1, 1), 512, 0, stream>>>(
        x2b, x2b, Wb4 + (size_t)50331648, 0, outX, nullptr, bp,
        4096, 4096, 4096, 1.0f, 1.0f, 16);
  } else {
    unsigned short* Wb = x2b + 33554432;
    cast_k<<<2048, 256, 0, stream>>>(x1, x1b, 8388608);
    cast_k<<<2048, 256, 0, stream>>>(x2, x2b, 8388608);
    cast_k<<<2048, 256, 0, stream>>>(Wq, Wb, 4194304);
    gemm256<0><<<dim3(512, 1, 1), 512, 0, stream>>>(
        x1b, x1b, Wb, 0, nullptr, Qt, nullptr, 4096, 4096, 4096, SCALE, SCALE, 16);
    cast_k<<<2048, 256, 0, stream>>>(Wk, Wb, 4194304);
    gemm256<0><<<dim3(512, 1, 1), 512, 0, stream>>>(
        x2b, x2b, Wb, 0, nullptr, Kt, nullptr, 4096, 4096, 4096, 1.0f, 1.0f, 16);
    cast_k<<<2048, 256, 0, stream>>>(Wv, Wb, 4194304);
    gemm256<0><<<dim3(512, 1, 1), 512, 0, stream>>>(
        x2b, x2b, Wb, 0, nullptr, Vt, nullptr, 4096, 4096, 4096, 1.0f, 1.0f, 16);
    attn_fused<<<dim3(4, 512), 256, 0, stream>>>(Qt, Kt, Vt, outA, x2b);
    cast_k<<<2048, 256, 0, stream>>>(Wp, Wb, 4194304);
    gemm256<3><<<dim3(512, 1, 1), 512, 0, stream>>>(
        x2b, x2b, Wb, 0, outX, nullptr, bp, 4096, 4096, 4096, 1.0f, 1.0f, 16);
  }
}

// Round 15
// 1267.154 us; speedup vs baseline: 8.6119x; 8.6119x over previous
//
#include <hip/hip_runtime.h>

typedef __attribute__((ext_vector_type(4))) float f32x4;
typedef __attribute__((ext_vector_type(8))) short short8;
typedef __attribute__((ext_vector_type(4))) unsigned short ushort4v;

__device__ __forceinline__ unsigned short rne_bf16(float f) {
  unsigned int u = __builtin_bit_cast(unsigned int, f);
  u += 0x7FFFu + ((u >> 16) & 1u);
  return (unsigned short)(u >> 16);
}

__device__ __forceinline__ void async16(void* lds, const void* g) {
  __builtin_amdgcn_global_load_lds(
      (const __attribute__((address_space(1))) void*)g,
      (__attribute__((address_space(3))) void*)lds, 16, 0, 0);
}

__device__ __forceinline__ f32x4 mfma16(short8 a, short8 b, f32x4 c) {
  return __builtin_amdgcn_mfma_f32_16x16x32_bf16(a, b, c, 0, 0, 0);
}

// ---------------- f32 -> bf16 cast (vectorized, grid-stride) ----------------
__global__ __launch_bounds__(256) void cast_k(const float* __restrict__ in,
                                              unsigned short* __restrict__ out,
                                              int n4) {
  int stride = gridDim.x * 256;
  for (int i = blockIdx.x * 256 + threadIdx.x; i < n4; i += stride) {
    float4 v = ((const float4*)in)[i];
    ushort4v o = {rne_bf16(v.x), rne_bf16(v.y), rne_bf16(v.z), rne_bf16(v.w)};
    ((ushort4v*)out)[i] = o;
  }
}

// ---------------- all-inputs cast in ONE dispatch (big-ws path) --------------
__global__ __launch_bounds__(256) void cast_all(const float* __restrict__ x1,
                                                const float* __restrict__ x2,
                                                const float* __restrict__ Wq,
                                                const float* __restrict__ Wk,
                                                const float* __restrict__ Wv,
                                                const float* __restrict__ Wp,
                                                unsigned short* __restrict__ x1b,
                                                unsigned short* __restrict__ x2b,
                                                unsigned short* __restrict__ Wb4) {
  const int stride = gridDim.x * 256;
  for (int i = blockIdx.x * 256 + threadIdx.x; i < 33554432; i += stride) {
    const float* src;
    unsigned short* dst;
    int off;
    if (i < 8388608) {
      src = x1; dst = x1b; off = i;
    } else if (i < 16777216) {
      src = x2; dst = x2b; off = i - 8388608;
    } else {
      const int w = (i - 16777216) >> 22;
      off = (i - 16777216) & 4194303;
      src = (w == 0) ? Wq : (w == 1) ? Wk : (w == 2) ? Wv : Wp;
      dst = Wb4 + (size_t)w * 16777216;
    }
    float4 v = ((const float4*)src)[off];
    ushort4v o = {rne_bf16(v.x), rne_bf16(v.y), rne_bf16(v.z), rne_bf16(v.w)};
    ((ushort4v*)dst)[off] = o;
  }
}

// ============ 256x256-tile GEMM: C = A @ B^T (bf16 in, K%64==0, K>=128) ======
// R10-proven structure (best measured: 1050 TF, 0 bank conflicts): 16x16x32
// MFMA, 8 waves (2Mx4N), 128 KiB LDS as 4 rotating 32KB regions (region Q at
// ((Q>>1)&1)*32768 + (Q&1)*8192; A there, B at +16384 shorts); phase P stages
// region P+3; per-phase counted vmcnt(4); frag reads at head of consuming
// phase (after the publish barrier); bf double-buffered one phase ahead.
// NOTE (R14 lesson): this tile REQUIRES 1 block/CU — acc[8][4]=128 regs +
// ~108 arch regs on the unified gfx950 file; any launch_bounds forcing 2
// blocks/CU (128-reg cap) spills the accumulator to scratch (25 GB writes).
// blockIdx.z selects (A, W, dst, scale) for the merged-QKV launch.
// MODE 0: QKV proj -> bf16 head-transposed dst[(b*16+h)][i][tok], *scale
// MODE 3: out proj -> f32 outF[m*4096+n] + bias[n]
template <int MODE>
__global__ __launch_bounds__(512, 2) void gemm256(const unsigned short* __restrict__ A1,
                                                  const unsigned short* __restrict__ A2,
                                                  const unsigned short* __restrict__ Bb,
                                                  size_t wstride,
                                                  float* __restrict__ outF,
                                                  unsigned short* __restrict__ outB0,
                                                  const float* __restrict__ bias,
                                                  int K, int lda, int ldb,
                                                  float scale0, float scale1, int gx) {
  __shared__ unsigned short lds[65536];  // 128 KiB
  const int tid = threadIdx.x;
  const int lane = tid & 63;
  const int wid = tid >> 6;
  const int wm = wid >> 2;  // 0..1 -> 128 rows each
  const int wn = wid & 3;   // 0..3 -> 64 cols each
  const int z = blockIdx.z;
  const unsigned short* A = z ? A2 : A1;
  const unsigned short* B = Bb + (size_t)z * wstride;
  unsigned short* outB = (MODE == 0) ? outB0 + (size_t)z * 33554432 : outB0;
  const float scale = z ? scale1 : scale0;
  int lin = blockIdx.x;
  lin = (lin & 7) * (gridDim.x >> 3) + (lin >> 3);  // XCD swizzle (grid%8==0)
  const int bx = lin % gx;
  const int by = lin / gx;
  const int m0 = by * 256, n0 = bx * 256;
  const int NT = K >> 6;

  // staging: thread t covers LDS slot p = tid (+512): row=p>>2, chunk=p&3
  const int gsw8 = (((tid & 3) ^ ((tid >> 3) & 3))) * 8;  // pre-swizzled col
  const unsigned short* gA = A + (size_t)(m0 + (tid >> 2)) * lda + gsw8;
  const unsigned short* gB = B + (size_t)(n0 + (tid >> 2)) * ldb + gsw8;
  const size_t astep = (size_t)128 * lda;
  const size_t bstep = (size_t)128 * ldb;
  unsigned short* ld0 = &lds[tid * 8];

#define STG(Q) do { \
    const int kt_ = ((Q) >> 1) * 64 + ((Q) & 1) * 32; \
    const int off_ = (((Q) >> 1) & 1) * 32768 + ((Q) & 1) * 8192; \
    const unsigned short* sA_ = gA + kt_; \
    unsigned short* dA_ = ld0 + off_; \
    async16(dA_, sA_); async16(dA_ + 4096, sA_ + astep); \
    const unsigned short* sB_ = gB + kt_; \
    unsigned short* dB_ = ld0 + 16384 + off_; \
    async16(dB_, sB_); async16(dB_ + 4096, sB_ + bstep); } while (0)

  // ds_read addresses (swizzled chunk; conflict-free)
  const int rl = lane & 15;
  const int ch = (lane >> 4) ^ ((rl >> 1) & 3);
  const int aidx = wm * 4096 + rl * 32 + ch * 8;           // + base + r*512
  const int bidx = 16384 + wn * 2048 + rl * 32 + ch * 8;   // + base + s*512

  short8 af[8], bf0[4], bf1[4];
#define READ_A(base) do { \
    _Pragma("unroll") \
    for (int r_ = 0; r_ < 8; ++r_) af[r_] = *(const short8*)&lds[(base) + aidx + r_ * 512]; \
  } while (0)
#define READ_B(base, dst) do { \
    _Pragma("unroll") \
    for (int s_ = 0; s_ < 4; ++s_) dst[s_] = *(const short8*)&lds[(base) + bidx + s_ * 512]; \
  } while (0)

  f32x4 acc[8][4];
#pragma unroll
  for (int r = 0; r < 8; ++r)
#pragma unroll
    for (int s = 0; s < 4; ++s) acc[r][s] = (f32x4){0.f, 0.f, 0.f, 0.f};

#define MFMA32(bfX) do { \
    __builtin_amdgcn_s_setprio(1); \
    _Pragma("unroll") \
    for (int r_ = 0; r_ < 8; ++r_) \
      _Pragma("unroll") \
      for (int s_ = 0; s_ < 4; ++s_) acc[r_][s_] = mfma16(af[r_], bfX[s_], acc[r_][s_]); \
    __builtin_amdgcn_s_setprio(0); \
  } while (0)

  // ---- prologue: stage phases 0,1,2; retire 0,1; publish; prefetch bf(ph0)
  STG(0); STG(1); STG(2);
  asm volatile("s_waitcnt vmcnt(4)" ::: "memory");
  __builtin_amdgcn_s_barrier();
  READ_B(0, bf0);

  for (int t = 0; t < NT; ++t) {
    const int bb = (t & 1) * 32768;
    // ---- phase A (P=2t, kh0): consume bf0, prefetch bf1
    READ_A(bb);
    READ_B(bb + 8192, bf1);            // ph 2t+1 (same tile, staged with it)
    if (t + 1 < NT) STG(2 * t + 3);    // tile t+1, kh1
    __builtin_amdgcn_sched_barrier(0);
    MFMA32(bf0);
    if (t + 1 < NT) asm volatile("s_waitcnt vmcnt(4)" ::: "memory");
    else            asm volatile("s_waitcnt vmcnt(0)" ::: "memory");
    __builtin_amdgcn_s_barrier();
    // ---- phase B (P=2t+1, kh1): consume bf1, prefetch bf0
    READ_A(bb + 8192);
    if (t + 1 < NT) {
      READ_B(((t + 1) & 1) * 32768, bf0);  // ph 2t+2
      if (t + 2 < NT) STG(2 * t + 4);      // tile t+2, kh0
    }
    __builtin_amdgcn_sched_barrier(0);
    MFMA32(bf1);
    if (t + 1 < NT) {
      if (t + 2 < NT) asm volatile("s_waitcnt vmcnt(4)" ::: "memory");
      else            asm volatile("s_waitcnt vmcnt(0)" ::: "memory");
      __builtin_amdgcn_s_barrier();
    }
  }
#undef STG
#undef READ_A
#undef READ_B
#undef MFMA32

  // ---- epilogue: C frag col = lane&15, row = (lane>>4)*4 + j
  const int fcol = lane & 15;
  const int frow = (lane >> 4) * 4;
#pragma unroll
  for (int r = 0; r < 8; ++r) {
#pragma unroll
    for (int s = 0; s < 4; ++s) {
      f32x4 v = acc[r][s];
      const int m = m0 + wm * 128 + r * 16 + frow;
      const int n = n0 + wn * 64 + s * 16 + fcol;
      if (MODE == 0) {
        ushort4v p;
#pragma unroll
        for (int j = 0; j < 4; ++j) p[j] = rne_bf16(v[j] * scale);
        size_t d = ((size_t)((m >> 8) * 16 + (n >> 8))) * 65536 +
                   (size_t)(n & 255) * 256 + (m & 255);
        *(ushort4v*)&outB[d] = p;
      } else {
        float bv = bias[n];
#pragma unroll
        for (int j = 0; j < 4; ++j) outF[(size_t)(m + j) * 4096 + n] = v[j] + bv;
      }
    }
  }
}

// ============ fused per-head attention: S = Qt@Kt^T, softmax, out = P@Vt^T ===
// (unchanged — near HBM floor)
__global__ __launch_bounds__(256) void attn_fused(const unsigned short* __restrict__ Qt,
                                                  const unsigned short* __restrict__ Kt,
                                                  const unsigned short* __restrict__ Vt,
                                                  float* __restrict__ outA,
                                                  unsigned short* __restrict__ outXb) {
  __shared__ unsigned short sh[34560];
  const int tid = threadIdx.x;
  const int lane = tid & 63;
  const int wid = tid >> 6;
  const int z = blockIdx.y;
  const int m0 = blockIdx.x * 64;
  const int wm = wid >> 1;
  const int wn = wid & 1;
  const int fcol = lane & 15;
  const int kslot = (lane >> 4) * 8;
  const int frow = (lane >> 4) * 4;

  const unsigned short* Qh = Qt + (size_t)z * 65536;
  const unsigned short* Kh = Kt + (size_t)z * 65536;
  const unsigned short* Vh = Vt + (size_t)z * 65536;
  float* redM = (float*)&sh[33536];
  float* redS = redM + 128;

  f32x4 acc[2][8];
#pragma unroll
  for (int r = 0; r < 2; ++r)
#pragma unroll
    for (int s = 0; s < 8; ++s) acc[r][s] = (f32x4){0.f, 0.f, 0.f, 0.f};

  {
    const int arow = tid >> 2;
    const int acol = (tid & 3) * 8;
    const unsigned short* gQ = Qh + (size_t)(m0 + arow) * 256 + acol;
    const unsigned short* gK = Kh + (size_t)arow * 256 + acol;
    unsigned short* lA = &sh[tid * 8];
    unsigned short* lB = &sh[2048 + tid * 8];

    for (int kt = 0; kt < 256; kt += 32) {
      __syncthreads();
      async16(lA, gQ + kt);
      async16(lB, gK + kt);
      async16(lB + 2048, gK + (size_t)64 * 256 + kt);
      async16(lB + 4096, gK + (size_t)128 * 256 + kt);
      async16(lB + 6144, gK + (size_t)192 * 256 + kt);
      __syncthreads();

      short8 a[2], b[8];
#pragma unroll
      for (int r = 0; r < 2; ++r)
        a[r] = *(const short8*)&sh[(wm * 32 + r * 16 + fcol) * 32 + kslot];
#pragma unroll
      for (int s = 0; s < 8; ++s)
        b[s] = *(const short8*)&sh[2048 + (wn * 128 + s * 16 + fcol) * 32 + kslot];
#pragma unroll
      for (int r = 0; r < 2; ++r)
#pragma unroll
        for (int s = 0; s < 8; ++s)
          acc[r][s] = mfma16(a[r], b[s], acc[r][s]);
    }
  }
  __syncthreads();

#pragma unroll
  for (int r = 0; r < 2; ++r) {
#pragma unroll
    for (int j = 0; j < 4; ++j) {
      float m = acc[r][0][j];
#pragma unroll
      for (int s = 1; s < 8; ++s) m = fmaxf(m, acc[r][s][j]);
#pragma unroll
      for (int off = 1; off < 16; off <<= 1) m = fmaxf(m, __shfl_xor(m, off, 64));
      if (fcol == 0) redM[(wm * 32 + r * 16 + frow + j) * 2 + wn] = m;
    }
  }
  __syncthreads();
#pragma unroll
  for (int r = 0; r < 2; ++r) {
#pragma unroll
    for (int j = 0; j < 4; ++j) {
      const int rl = wm * 32 + r * 16 + frow + j;
      const float m = fmaxf(redM[rl * 2 + 0], redM[rl * 2 + 1]);
      float sum = 0.f;
#pragma unroll
      for (int s = 0; s < 8; ++s) {
        float e = __expf(acc[r][s][j] - m);
        acc[r][s][j] = e;
        sum += e;
      }
#pragma unroll
      for (int off = 1; off < 16; off <<= 1) sum += __shfl_xor(sum, off, 64);
      if (fcol == 0) redS[rl * 2 + wn] = sum;
    }
  }
  __syncthreads();
#pragma unroll
  for (int r = 0; r < 2; ++r) {
#pragma unroll
    for (int j = 0; j < 4; ++j) {
      const int rl = wm * 32 + r * 16 + frow + j;
      const float inv = 1.0f / (redS[rl * 2 + 0] + redS[rl * 2 + 1]);
      const size_t rowo = (size_t)z * 65536 + (size_t)(m0 + rl) * 256;
#pragma unroll
      for (int s = 0; s < 8; ++s) {
        const int col = wn * 128 + s * 16 + fcol;
        const float p = acc[r][s][j] * inv;
        outA[rowo + col] = p;
        sh[16384 + rl * 268 + col] = rne_bf16(p);
      }
    }
  }
  __syncthreads();

  const unsigned short* gV = Vh + (size_t)(tid >> 2) * 256 + (tid & 3) * 8;
#define STGV(kt, vb) do { \
    _Pragma("unroll") \
    for (int k_ = 0; k_ < 4; ++k_) \
      async16(&sh[(vb) + tid * 8 + k_ * 2048], \
              gV + (size_t)k_ * 64 * 256 + (kt) * 32); } while (0)

  STGV(0, 0); STGV(1, 8192);
  asm volatile("s_waitcnt vmcnt(4)" ::: "memory");
  __builtin_amdgcn_s_barrier();

  f32x4 acc2[2][8];
#pragma unroll
  for (int r = 0; r < 2; ++r)
#pragma unroll
    for (int s = 0; s < 8; ++s) acc2[r][s] = (f32x4){0.f, 0.f, 0.f, 0.f};

  for (int kt = 0; kt < 8; ++kt) {
    const int vb = (kt & 1) * 8192;
    short8 a2[2], b2[8];
#pragma unroll
    for (int r = 0; r < 2; ++r)
      a2[r] = *(const short8*)&sh[16384 + (wm * 32 + r * 16 + fcol) * 268 + kt * 32 + kslot];
#pragma unroll
    for (int s = 0; s < 8; ++s)
      b2[s] = *(const short8*)&sh[vb + (wn * 128 + s * 16 + fcol) * 32 + kslot];
#pragma unroll
    for (int r = 0; r < 2; ++r)
#pragma unroll
      for (int s = 0; s < 8; ++s)
        acc2[r][s] = mfma16(a2[r], b2[s], acc2[r][s]);
    __builtin_amdgcn_s_barrier();
    if (kt + 2 < 8) {
      STGV(kt + 2, vb);
      asm volatile("s_waitcnt vmcnt(4)" ::: "memory");
    } else {
      asm volatile("s_waitcnt vmcnt(0)" ::: "memory");
    }
    __builtin_amdgcn_s_barrier();
  }
#undef STGV

#pragma unroll
  for (int r = 0; r < 2; ++r) {
#pragma unroll
    for (int s = 0; s < 8; ++s) {
      f32x4 v = acc2[r][s];
      const int i0 = m0 + wm * 32 + r * 16 + frow;
      const int c = wn * 128 + s * 16 + fcol;
#pragma unroll
      for (int j = 0; j < 4; ++j) {
        size_t d = ((size_t)((z >> 4) * 256 + i0 + j)) * 4096 + (z & 15) * 256 + c;
        outXb[d] = rne_bf16(v[j]);
      }
    }
  }
}

// -----------------------------------------------------------------------------
extern "C" void kernel_launch(void* const* d_in, const int* in_sizes, int n_in,
                              void* d_out, int out_size, void* d_ws, size_t ws_size,
                              hipStream_t stream) {
  const float* x1 = (const float*)d_in[0];
  const float* x2 = (const float*)d_in[1];
  const float* Wq = (const float*)d_in[2];
  const float* Wk = (const float*)d_in[3];
  const float* Wv = (const float*)d_in[4];
  const float* Wp = (const float*)d_in[5];
  const float* bp = (const float*)d_in[6];

  float* outX = (float*)d_out;                   // x: [8192,4096] f32
  float* outA = outX + (size_t)33554432;         // attn: [512,256,256] f32

  unsigned short* Qt  = (unsigned short*)d_ws;   // [512][256][256] head-transposed
  unsigned short* Kt  = Qt + 33554432;
  unsigned short* Vt  = Kt + 33554432;
  unsigned short* x1b = Vt + 33554432;           // x1 bf16
  unsigned short* x2b = x1b + 33554432;          // x2 bf16; later out_x bf16

  const float SCALE = 0.0625f;  // 256^-0.5
  const bool big = ws_size >= 469762048ULL;

  if (big) {
    unsigned short* Wb4 = x2b + 33554432;        // [4][4096][4096] bf16
    cast_all<<<2048, 256, 0, stream>>>(x1, x2, Wq, Wk, Wv, Wp, x1b, x2b, Wb4);
    // merged QKV: z=0: Q=(x1b@Wq^T)*SCALE->Qt; z=1: K->Kt; z=2: V->Vt
    gemm256<0><<<dim3(512, 1, 3), 512, 0, stream>>>(
        x1b, x2b, Wb4, (size_t)16777216, nullptr, Qt, nullptr,
        4096, 4096, 4096, SCALE, 1.0f, 16);
    attn_fused<<<dim3(4, 512), 256, 0, stream>>>(Qt, Kt, Vt, outA, x2b);
    // x = out @ Wp^T + bp -> d_out
    gemm256<3><<<dim3(512, 1, 1), 512, 0, stream>>>(
        x2b, x2b, Wb4 + (size_t)50331648, 0, outX, nullptr, bp,
        4096, 4096, 4096, 1.0f, 1.0f, 16);
  } else {
    unsigned short* Wb = x2b + 33554432;
    cast_k<<<2048, 256, 0, stream>>>(x1, x1b, 8388608);
    cast_k<<<2048, 256, 0, stream>>>(x2, x2b, 8388608);
    cast_k<<<2048, 256, 0, stream>>>(Wq, Wb, 4194304);
    gemm256<0><<<dim3(512, 1, 1), 512, 0, stream>>>(
        x1b, x1b, Wb, 0, nullptr, Qt, nullptr, 4096, 4096, 4096, SCALE, SCALE, 16);
    cast_k<<<2048, 256, 0, stream>>>(Wk, Wb, 4194304);
    gemm256<0><<<dim3(512, 1, 1), 512, 0, stream>>>(
        x2b, x2b, Wb, 0, nullptr, Kt, nullptr, 4096, 4096, 4096, 1.0f, 1.0f, 16);
    cast_k<<<2048, 256, 0, stream>>>(Wv, Wb, 4194304);
    gemm256<0><<<dim3(512, 1, 1), 512, 0, stream>>>(
        x2b, x2b, Wb, 0, nullptr, Vt, nullptr, 4096, 4096, 4096, 1.0f, 1.0f, 16);
    attn_fused<<<dim3(4, 512), 256, 0, stream>>>(Qt, Kt, Vt, outA, x2b);
    cast_k<<<2048, 256, 0, stream>>>(Wp, Wb, 4194304);
    gemm256<3><<<dim3(512, 1, 1), 512, 0, stream>>>(
        x2b, x2b, Wb, 0, outX, nullptr, bp, 4096, 4096, 4096, 1.0f, 1.0f, 16);
  }
}

// Round 16
// 1243.568 us; speedup vs baseline: 8.7752x; 1.0190x over previous
//
#include <hip/hip_runtime.h>

typedef __attribute__((ext_vector_type(4))) float f32x4;
typedef __attribute__((ext_vector_type(8))) short short8;
typedef __attribute__((ext_vector_type(4))) unsigned short ushort4v;

__device__ __forceinline__ unsigned short rne_bf16(float f) {
  unsigned int u = __builtin_bit_cast(unsigned int, f);
  u += 0x7FFFu + ((u >> 16) & 1u);
  return (unsigned short)(u >> 16);
}

__device__ __forceinline__ void async16(void* lds, const void* g) {
  __builtin_amdgcn_global_load_lds(
      (const __attribute__((address_space(1))) void*)g,
      (__attribute__((address_space(3))) void*)lds, 16, 0, 0);
}

__device__ __forceinline__ f32x4 mfma16(short8 a, short8 b, f32x4 c) {
  return __builtin_amdgcn_mfma_f32_16x16x32_bf16(a, b, c, 0, 0, 0);
}

// ---------------- f32 -> bf16 cast (vectorized, grid-stride) ----------------
__global__ __launch_bounds__(256) void cast_k(const float* __restrict__ in,
                                              unsigned short* __restrict__ out,
                                              int n4) {
  int stride = gridDim.x * 256;
  for (int i = blockIdx.x * 256 + threadIdx.x; i < n4; i += stride) {
    float4 v = ((const float4*)in)[i];
    ushort4v o = {rne_bf16(v.x), rne_bf16(v.y), rne_bf16(v.z), rne_bf16(v.w)};
    ((ushort4v*)out)[i] = o;
  }
}

// ---------------- all-inputs cast in ONE dispatch (big-ws path) --------------
__global__ __launch_bounds__(256) void cast_all(const float* __restrict__ x1,
                                                const float* __restrict__ x2,
                                                const float* __restrict__ Wq,
                                                const float* __restrict__ Wk,
                                                const float* __restrict__ Wv,
                                                const float* __restrict__ Wp,
                                                unsigned short* __restrict__ x1b,
                                                unsigned short* __restrict__ x2b,
                                                unsigned short* __restrict__ Wb4) {
  const int stride = gridDim.x * 256;
  for (int i = blockIdx.x * 256 + threadIdx.x; i < 33554432; i += stride) {
    const float* src;
    unsigned short* dst;
    int off;
    if (i < 8388608) {
      src = x1; dst = x1b; off = i;
    } else if (i < 16777216) {
      src = x2; dst = x2b; off = i - 8388608;
    } else {
      const int w = (i - 16777216) >> 22;
      off = (i - 16777216) & 4194303;
      src = (w == 0) ? Wq : (w == 1) ? Wk : (w == 2) ? Wv : Wp;
      dst = Wb4 + (size_t)w * 16777216;
    }
    float4 v = ((const float4*)src)[off];
    ushort4v o = {rne_bf16(v.x), rne_bf16(v.y), rne_bf16(v.z), rne_bf16(v.w)};
    ((ushort4v*)dst)[off] = o;
  }
}

// ============ 256x256-tile GEMM: C = A @ B^T (bf16 in, K%64==0, K>=128) ======
// R10-proven K-loop (best measured; 0 bank conflicts). NEW (R16): within each
// XCD's 64-block chunk, map blocks to an 8x8 (bx,by) SQUARE instead of 4x16
// rows: per-chunk fetch 8 A-panels + 8 B-panels (32MB) vs 4+16 (40MB), and the
// 8-XCD live working set fits L3. Requires grid == 512 and gx == 16 (both
// launches satisfy this); bijection verified: xcd 0..7, q 0..63 ->
// bx = (xcd&1)*8 + (q&7) in 0..15, by = (xcd>>1)*8 + (q>>3) in 0..31.
// NOTE (R14): tile requires 1 block/CU (acc 128 + ~108 arch regs, unified RF).
// blockIdx.z selects (A, W, dst, scale) for the merged-QKV launch.
// MODE 0: QKV proj -> bf16 head-transposed dst[(b*16+h)][i][tok], *scale
// MODE 3: out proj -> f32 outF[m*4096+n] + bias[n]
template <int MODE>
__global__ __launch_bounds__(512, 2) void gemm256(const unsigned short* __restrict__ A1,
                                                  const unsigned short* __restrict__ A2,
                                                  const unsigned short* __restrict__ Bb,
                                                  size_t wstride,
                                                  float* __restrict__ outF,
                                                  unsigned short* __restrict__ outB0,
                                                  const float* __restrict__ bias,
                                                  int K, int lda, int ldb,
                                                  float scale0, float scale1, int gx) {
  __shared__ unsigned short lds[65536];  // 128 KiB
  const int tid = threadIdx.x;
  const int lane = tid & 63;
  const int wid = tid >> 6;
  const int wm = wid >> 2;  // 0..1 -> 128 rows each
  const int wn = wid & 3;   // 0..3 -> 64 cols each
  const int z = blockIdx.z;
  const unsigned short* A = z ? A2 : A1;
  const unsigned short* B = Bb + (size_t)z * wstride;
  unsigned short* outB = (MODE == 0) ? outB0 + (size_t)z * 33554432 : outB0;
  const float scale = z ? scale1 : scale0;
  // ---- XCD swizzle + 8x8 square chunk (grid 512, gx 16)
  const int xcd = blockIdx.x & 7;
  const int q = blockIdx.x >> 3;      // 0..63: chunk-local index, same XCD
  const int bx = (xcd & 1) * 8 + (q & 7);
  const int by = (xcd >> 1) * 8 + (q >> 3);
  const int m0 = by * 256, n0 = bx * 256;
  const int NT = K >> 6;
  (void)gx;

  // staging: thread t covers LDS slot p = tid (+512): row=p>>2, chunk=p&3
  const int gsw8 = (((tid & 3) ^ ((tid >> 3) & 3))) * 8;  // pre-swizzled col
  const unsigned short* gA = A + (size_t)(m0 + (tid >> 2)) * lda + gsw8;
  const unsigned short* gB = B + (size_t)(n0 + (tid >> 2)) * ldb + gsw8;
  const size_t astep = (size_t)128 * lda;
  const size_t bstep = (size_t)128 * ldb;
  unsigned short* ld0 = &lds[tid * 8];

#define STG(Q) do { \
    const int kt_ = ((Q) >> 1) * 64 + ((Q) & 1) * 32; \
    const int off_ = (((Q) >> 1) & 1) * 32768 + ((Q) & 1) * 8192; \
    const unsigned short* sA_ = gA + kt_; \
    unsigned short* dA_ = ld0 + off_; \
    async16(dA_, sA_); async16(dA_ + 4096, sA_ + astep); \
    const unsigned short* sB_ = gB + kt_; \
    unsigned short* dB_ = ld0 + 16384 + off_; \
    async16(dB_, sB_); async16(dB_ + 4096, sB_ + bstep); } while (0)

  // ds_read addresses (swizzled chunk; conflict-free)
  const int rl = lane & 15;
  const int ch = (lane >> 4) ^ ((rl >> 1) & 3);
  const int aidx = wm * 4096 + rl * 32 + ch * 8;           // + base + r*512
  const int bidx = 16384 + wn * 2048 + rl * 32 + ch * 8;   // + base + s*512

  short8 af[8], bf0[4], bf1[4];
#define READ_A(base) do { \
    _Pragma("unroll") \
    for (int r_ = 0; r_ < 8; ++r_) af[r_] = *(const short8*)&lds[(base) + aidx + r_ * 512]; \
  } while (0)
#define READ_B(base, dst) do { \
    _Pragma("unroll") \
    for (int s_ = 0; s_ < 4; ++s_) dst[s_] = *(const short8*)&lds[(base) + bidx + s_ * 512]; \
  } while (0)

  f32x4 acc[8][4];
#pragma unroll
  for (int r = 0; r < 8; ++r)
#pragma unroll
    for (int s = 0; s < 4; ++s) acc[r][s] = (f32x4){0.f, 0.f, 0.f, 0.f};

#define MFMA32(bfX) do { \
    __builtin_amdgcn_s_setprio(1); \
    _Pragma("unroll") \
    for (int r_ = 0; r_ < 8; ++r_) \
      _Pragma("unroll") \
      for (int s_ = 0; s_ < 4; ++s_) acc[r_][s_] = mfma16(af[r_], bfX[s_], acc[r_][s_]); \
    __builtin_amdgcn_s_setprio(0); \
  } while (0)

  // ---- prologue: stage phases 0,1,2; retire 0,1; publish; prefetch bf(ph0)
  STG(0); STG(1); STG(2);
  asm volatile("s_waitcnt vmcnt(4)" ::: "memory");
  __builtin_amdgcn_s_barrier();
  READ_B(0, bf0);

  for (int t = 0; t < NT; ++t) {
    const int bb = (t & 1) * 32768;
    // ---- phase A (P=2t, kh0): consume bf0, prefetch bf1
    READ_A(bb);
    READ_B(bb + 8192, bf1);            // ph 2t+1 (same tile, staged with it)
    if (t + 1 < NT) STG(2 * t + 3);    // tile t+1, kh1
    __builtin_amdgcn_sched_barrier(0);
    MFMA32(bf0);
    if (t + 1 < NT) asm volatile("s_waitcnt vmcnt(4)" ::: "memory");
    else            asm volatile("s_waitcnt vmcnt(0)" ::: "memory");
    __builtin_amdgcn_s_barrier();
    // ---- phase B (P=2t+1, kh1): consume bf1, prefetch bf0
    READ_A(bb + 8192);
    if (t + 1 < NT) {
      READ_B(((t + 1) & 1) * 32768, bf0);  // ph 2t+2
      if (t + 2 < NT) STG(2 * t + 4);      // tile t+2, kh0
    }
    __builtin_amdgcn_sched_barrier(0);
    MFMA32(bf1);
    if (t + 1 < NT) {
      if (t + 2 < NT) asm volatile("s_waitcnt vmcnt(4)" ::: "memory");
      else            asm volatile("s_waitcnt vmcnt(0)" ::: "memory");
      __builtin_amdgcn_s_barrier();
    }
  }
#undef STG
#undef READ_A
#undef READ_B
#undef MFMA32

  // ---- epilogue: C frag col = lane&15, row = (lane>>4)*4 + j
  const int fcol = lane & 15;
  const int frow = (lane >> 4) * 4;
#pragma unroll
  for (int r = 0; r < 8; ++r) {
#pragma unroll
    for (int s = 0; s < 4; ++s) {
      f32x4 v = acc[r][s];
      const int m = m0 + wm * 128 + r * 16 + frow;
      const int n = n0 + wn * 64 + s * 16 + fcol;
      if (MODE == 0) {
        ushort4v p;
#pragma unroll
        for (int j = 0; j < 4; ++j) p[j] = rne_bf16(v[j] * scale);
        size_t d = ((size_t)((m >> 8) * 16 + (n >> 8))) * 65536 +
                   (size_t)(n & 255) * 256 + (m & 255);
        *(ushort4v*)&outB[d] = p;
      } else {
        float bv = bias[n];
#pragma unroll
        for (int j = 0; j < 4; ++j) outF[(size_t)(m + j) * 4096 + n] = v[j] + bv;
      }
    }
  }
}

// ============ fused per-head attention: S = Qt@Kt^T, softmax, out = P@Vt^T ===
// (unchanged — near HBM floor)
__global__ __launch_bounds__(256) void attn_fused(const unsigned short* __restrict__ Qt,
                                                  const unsigned short* __restrict__ Kt,
                                                  const unsigned short* __restrict__ Vt,
                                                  float* __restrict__ outA,
                                                  unsigned short* __restrict__ outXb) {
  __shared__ unsigned short sh[34560];
  const int tid = threadIdx.x;
  const int lane = tid & 63;
  const int wid = tid >> 6;
  const int z = blockIdx.y;
  const int m0 = blockIdx.x * 64;
  const int wm = wid >> 1;
  const int wn = wid & 1;
  const int fcol = lane & 15;
  const int kslot = (lane >> 4) * 8;
  const int frow = (lane >> 4) * 4;

  const unsigned short* Qh = Qt + (size_t)z * 65536;
  const unsigned short* Kh = Kt + (size_t)z * 65536;
  const unsigned short* Vh = Vt + (size_t)z * 65536;
  float* redM = (float*)&sh[33536];
  float* redS = redM + 128;

  f32x4 acc[2][8];
#pragma unroll
  for (int r = 0; r < 2; ++r)
#pragma unroll
    for (int s = 0; s < 8; ++s) acc[r][s] = (f32x4){0.f, 0.f, 0.f, 0.f};

  {
    const int arow = tid >> 2;
    const int acol = (tid & 3) * 8;
    const unsigned short* gQ = Qh + (size_t)(m0 + arow) * 256 + acol;
    const unsigned short* gK = Kh + (size_t)arow * 256 + acol;
    unsigned short* lA = &sh[tid * 8];
    unsigned short* lB = &sh[2048 + tid * 8];

    for (int kt = 0; kt < 256; kt += 32) {
      __syncthreads();
      async16(lA, gQ + kt);
      async16(lB, gK + kt);
      async16(lB + 2048, gK + (size_t)64 * 256 + kt);
      async16(lB + 4096, gK + (size_t)128 * 256 + kt);
      async16(lB + 6144, gK + (size_t)192 * 256 + kt);
      __syncthreads();

      short8 a[2], b[8];
#pragma unroll
      for (int r = 0; r < 2; ++r)
        a[r] = *(const short8*)&sh[(wm * 32 + r * 16 + fcol) * 32 + kslot];
#pragma unroll
      for (int s = 0; s < 8; ++s)
        b[s] = *(const short8*)&sh[2048 + (wn * 128 + s * 16 + fcol) * 32 + kslot];
#pragma unroll
      for (int r = 0; r < 2; ++r)
#pragma unroll
        for (int s = 0; s < 8; ++s)
          acc[r][s] = mfma16(a[r], b[s], acc[r][s]);
    }
  }
  __syncthreads();

#pragma unroll
  for (int r = 0; r < 2; ++r) {
#pragma unroll
    for (int j = 0; j < 4; ++j) {
      float m = acc[r][0][j];
#pragma unroll
      for (int s = 1; s < 8; ++s) m = fmaxf(m, acc[r][s][j]);
#pragma unroll
      for (int off = 1; off < 16; off <<= 1) m = fmaxf(m, __shfl_xor(m, off, 64));
      if (fcol == 0) redM[(wm * 32 + r * 16 + frow + j) * 2 + wn] = m;
    }
  }
  __syncthreads();
#pragma unroll
  for (int r = 0; r < 2; ++r) {
#pragma unroll
    for (int j = 0; j < 4; ++j) {
      const int rl = wm * 32 + r * 16 + frow + j;
      const float m = fmaxf(redM[rl * 2 + 0], redM[rl * 2 + 1]);
      float sum = 0.f;
#pragma unroll
      for (int s = 0; s < 8; ++s) {
        float e = __expf(acc[r][s][j] - m);
        acc[r][s][j] = e;
        sum += e;
      }
#pragma unroll
      for (int off = 1; off < 16; off <<= 1) sum += __shfl_xor(sum, off, 64);
      if (fcol == 0) redS[rl * 2 + wn] = sum;
    }
  }
  __syncthreads();
#pragma unroll
  for (int r = 0; r < 2; ++r) {
#pragma unroll
    for (int j = 0; j < 4; ++j) {
      const int rl = wm * 32 + r * 16 + frow + j;
      const float inv = 1.0f / (redS[rl * 2 + 0] + redS[rl * 2 + 1]);
      const size_t rowo = (size_t)z * 65536 + (size_t)(m0 + rl) * 256;
#pragma unroll
      for (int s = 0; s < 8; ++s) {
        const int col = wn * 128 + s * 16 + fcol;
        const float p = acc[r][s][j] * inv;
        outA[rowo + col] = p;
        sh[16384 + rl * 268 + col] = rne_bf16(p);
      }
    }
  }
  __syncthreads();

  const unsigned short* gV = Vh + (size_t)(tid >> 2) * 256 + (tid & 3) * 8;
#define STGV(kt, vb) do { \
    _Pragma("unroll") \
    for (int k_ = 0; k_ < 4; ++k_) \
      async16(&sh[(vb) + tid * 8 + k_ * 2048], \
              gV + (size_t)k_ * 64 * 256 + (kt) * 32); } while (0)

  STGV(0, 0); STGV(1, 8192);
  asm volatile("s_waitcnt vmcnt(4)" ::: "memory");
  __builtin_amdgcn_s_barrier();

  f32x4 acc2[2][8];
#pragma unroll
  for (int r = 0; r < 2; ++r)
#pragma unroll
    for (int s = 0; s < 8; ++s) acc2[r][s] = (f32x4){0.f, 0.f, 0.f, 0.f};

  for (int kt = 0; kt < 8; ++kt) {
    const int vb = (kt & 1) * 8192;
    short8 a2[2], b2[8];
#pragma unroll
    for (int r = 0; r < 2; ++r)
      a2[r] = *(const short8*)&sh[16384 + (wm * 32 + r * 16 + fcol) * 268 + kt * 32 + kslot];
#pragma unroll
    for (int s = 0; s < 8; ++s)
      b2[s] = *(const short8*)&sh[vb + (wn * 128 + s * 16 + fcol) * 32 + kslot];
#pragma unroll
    for (int r = 0; r < 2; ++r)
#pragma unroll
      for (int s = 0; s < 8; ++s)
        acc2[r][s] = mfma16(a2[r], b2[s], acc2[r][s]);
    __builtin_amdgcn_s_barrier();
    if (kt + 2 < 8) {
      STGV(kt + 2, vb);
      asm volatile("s_waitcnt vmcnt(4)" ::: "memory");
    } else {
      asm volatile("s_waitcnt vmcnt(0)" ::: "memory");
    }
    __builtin_amdgcn_s_barrier();
  }
#undef STGV

#pragma unroll
  for (int r = 0; r < 2; ++r) {
#pragma unroll
    for (int s = 0; s < 8; ++s) {
      f32x4 v = acc2[r][s];
      const int i0 = m0 + wm * 32 + r * 16 + frow;
      const int c = wn * 128 + s * 16 + fcol;
#pragma unroll
      for (int j = 0; j < 4; ++j) {
        size_t d = ((size_t)((z >> 4) * 256 + i0 + j)) * 4096 + (z & 15) * 256 + c;
        outXb[d] = rne_bf16(v[j]);
      }
    }
  }
}

// -----------------------------------------------------------------------------
extern "C" void kernel_launch(void* const* d_in, const int* in_sizes, int n_in,
                              void* d_out, int out_size, void* d_ws, size_t ws_size,
                              hipStream_t stream) {
  const float* x1 = (const float*)d_in[0];
  const float* x2 = (const float*)d_in[1];
  const float* Wq = (const float*)d_in[2];
  const float* Wk = (const float*)d_in[3];
  const float* Wv = (const float*)d_in[4];
  const float* Wp = (const float*)d_in[5];
  const float* bp = (const float*)d_in[6];

  float* outX = (float*)d_out;                   // x: [8192,4096] f32
  float* outA = outX + (size_t)33554432;         // attn: [512,256,256] f32

  unsigned short* Qt  = (unsigned short*)d_ws;   // [512][256][256] head-transposed
  unsigned short* Kt  = Qt + 33554432;
  unsigned short* Vt  = Kt + 33554432;
  unsigned short* x1b = Vt + 33554432;           // x1 bf16
  unsigned short* x2b = x1b + 33554432;          // x2 bf16; later out_x bf16

  const float SCALE = 0.0625f;  // 256^-0.5
  const bool big = ws_size >= 469762048ULL;

  if (big) {
    unsigned short* Wb4 = x2b + 33554432;        // [4][4096][4096] bf16
    cast_all<<<4096, 256, 0, stream>>>(x1, x2, Wq, Wk, Wv, Wp, x1b, x2b, Wb4);
    // merged QKV: z=0: Q=(x1b@Wq^T)*SCALE->Qt; z=1: K->Kt; z=2: V->Vt
    gemm256<0><<<dim3(512, 1, 3), 512, 0, stream>>>(
        x1b, x2b, Wb4, (size_t)16777216, nullptr, Qt, nullptr,
        4096, 4096, 4096, SCALE, 1.0f, 16);
    attn_fused<<<dim3(4, 512), 256, 0, stream>>>(Qt, Kt, Vt, outA, x2b);
    // x = out @ Wp^T + bp -> d_out
    gemm256<3><<<dim3(512, 1, 1), 512, 0, stream>>>(
        x2b, x2b, Wb4 + (size_t)50331648, 0, outX, nullptr, bp,
        4096, 4096, 4096, 1.0f, 1.0f, 16);
  } else {
    unsigned short* Wb = x2b + 33554432;
    cast_k<<<2048, 256, 0, stream>>>(x1, x1b, 8388608);
    cast_k<<<2048, 256, 0, stream>>>(x2, x2b, 8388608);
    cast_k<<<2048, 256, 0, stream>>>(Wq, Wb, 4194304);
    gemm256<0><<<dim3(512, 1, 1), 512, 0, stream>>>(
        x1b, x1b, Wb, 0, nullptr, Qt, nullptr, 4096, 4096, 4096, SCALE, SCALE, 16);
    cast_k<<<2048, 256, 0, stream>>>(Wk, Wb, 4194304);
    gemm256<0><<<dim3(512, 1, 1), 512, 0, stream>>>(
        x2b, x2b, Wb, 0, nullptr, Kt, nullptr, 4096, 4096, 4096, 1.0f, 1.0f, 16);
    cast_k<<<2048, 256, 0, stream>>>(Wv, Wb, 4194304);
    gemm256<0><<<dim3(512, 1, 1), 512, 0, stream>>>(
        x2b, x2b, Wb, 0, nullptr, Vt, nullptr, 4096, 4096, 4096, 1.0f, 1.0f, 16);
    attn_fused<<<dim3(4, 512), 256, 0, stream>>>(Qt, Kt, Vt, outA, x2b);
    cast_k<<<2048, 256, 0, stream>>>(Wp, Wb, 4194304);
    gemm256<3><<<dim3(512, 1, 1), 512, 0, stream>>>(
        x2b, x2b, Wb, 0, outX, nullptr, bp, 4096, 4096, 4096, 1.0f, 1.0f, 16);
  }
}